// Round 5
// baseline (2061.833 us; speedup 1.0000x reference)
//
#include <hip/hip_runtime.h>
#include <hip/hip_bf16.h>
#include <math.h>

#define TB 256
#define SCAN_T 1024

__device__ __forceinline__ void atomic_add_f32(float* p, float v) {
    unsafeAtomicAdd(p, v);  // hardware global_atomic_add_f32
}

// Zero deg (N), hist (N), sums (256*32), cnt (256)
__global__ __launch_bounds__(TB) void zero_kernel(float* __restrict__ deg,
                                                  int* __restrict__ hist,
                                                  float* __restrict__ sums,
                                                  float* __restrict__ cnt,
                                                  int n_nodes) {
    int i = blockIdx.x * TB + threadIdx.x;
    if (i < n_nodes) { deg[i] = 0.0f; hist[i] = 0; }
    if (i < 256 * 32) sums[i] = 0.0f;
    if (i < 256) cnt[i] = 0.0f;
}

// Per-edge Gaussian weight + degree scatter + col histogram
__global__ __launch_bounds__(TB) void edge_weight_kernel(
    const int* __restrict__ row, const int* __restrict__ col,
    const float2* __restrict__ pos2,
    const float* __restrict__ s1p, const float* __restrict__ s2p,
    float* __restrict__ ew, float* __restrict__ deg, int* __restrict__ hist,
    int n_edges) {
    int e = blockIdx.x * TB + threadIdx.x;
    if (e >= n_edges) return;
    int r = row[e], c = col[e];
    float2 r0 = pos2[r * 3 + 0], r1 = pos2[r * 3 + 1], r2 = pos2[r * 3 + 2];
    float2 c0 = pos2[c * 3 + 0], c1 = pos2[c * 3 + 1], c2 = pos2[c * 3 + 2];
    float dx = r0.x - c0.x, dy = r0.y - c0.y, dz = r1.x - c1.x;
    float D = dx * dx + dy * dy + dz * dz;
    float dot = r1.y * c1.y + r2.x * c2.x + r2.y * c2.y;
    float t = 1.0f - dot;
    float T = t * t;
    float s1 = s1p[0], s2 = s2p[0];
    float w = expf(-(D * s1 * s1 + T * s2 * s2));
    ew[e] = w;
    atomic_add_f32(&deg[c], w);
    atomicAdd(&hist[c], 1);
}

// dinv = (deg+1)^-0.5, in place
__global__ __launch_bounds__(TB) void dinv_kernel(float* __restrict__ deg, int n) {
    int i = blockIdx.x * TB + threadIdx.x;
    if (i < n) deg[i] = 1.0f / sqrtf(deg[i] + 1.0f);
}

// Single-block dual exclusive scan: edges (hist) and segments (ceil(hist/8))
__global__ __launch_bounds__(SCAN_T) void scan_kernel(const int* __restrict__ hist,
                                                      int* __restrict__ ptr,
                                                      int* __restrict__ cursor,
                                                      int* __restrict__ segbase, int n) {
    __shared__ int pe[SCAN_T];
    __shared__ int ps[SCAN_T];
    int t = threadIdx.x;
    int chunk = (n + SCAN_T - 1) / SCAN_T;
    int beg = t * chunk;
    int end = min(beg + chunk, n);
    int se = 0, ss = 0;
    for (int i = beg; i < end; i++) { int h = hist[i]; se += h; ss += (h + 7) >> 3; }
    pe[t] = se; ps[t] = ss;
    __syncthreads();
    for (int off = 1; off < SCAN_T; off <<= 1) {
        int ve = (t >= off) ? pe[t - off] : 0;
        int vs = (t >= off) ? ps[t - off] : 0;
        __syncthreads();
        pe[t] += ve; ps[t] += vs;
        __syncthreads();
    }
    int re = (t == 0) ? 0 : pe[t - 1];
    int rs = (t == 0) ? 0 : ps[t - 1];
    for (int i = beg; i < end; i++) {
        int h = hist[i];
        ptr[i] = re; cursor[i] = re; segbase[i] = rs;
        re += h; rs += (h + 7) >> 3;
    }
    if (t == SCAN_T - 1) { ptr[n] = pe[SCAN_T - 1]; segbase[n] = ps[SCAN_T - 1]; }
}

// Scatter edges into padded per-segment layout: node c's j-th edge lands at
// seg slot segbase[c]*8 + j (segments of a node are contiguous).
__global__ __launch_bounds__(TB) void fill_kernel(
    const int* __restrict__ row, const int* __restrict__ col,
    const float* __restrict__ ew, const float* __restrict__ dinv,
    int* __restrict__ cursor, const int* __restrict__ ptr,
    const int* __restrict__ segbase,
    int* __restrict__ seg_rows, float* __restrict__ seg_norms, int n_edges) {
    int e = blockIdx.x * TB + threadIdx.x;
    if (e >= n_edges) return;
    int r = row[e], c = col[e];
    float nm = dinv[r] * ew[e] * dinv[c];
    int pos = atomicAdd(&cursor[c], 1);
    int j = pos - ptr[c];
    size_t a = (size_t)segbase[c] * 8 + j;
    seg_rows[a] = r;
    seg_norms[a] = nm;
}

// Per-node: write segment->node descriptors + zero the padded tail slots
__global__ __launch_bounds__(TB) void segfill_kernel(
    const int* __restrict__ ptr, const int* __restrict__ segbase,
    int* __restrict__ desc, int* __restrict__ seg_rows,
    float* __restrict__ seg_norms, int n_nodes) {
    int nd = blockIdx.x * TB + threadIdx.x;
    if (nd >= n_nodes) return;
    int beg = ptr[nd], end = ptr[nd + 1];
    int deg = end - beg;
    int sb = segbase[nd];
    int nseg = (deg + 7) >> 3;
    for (int i = 0; i < nseg; i++) desc[sb + i] = nd;
    size_t base = (size_t)sb * 8;
    for (int j = deg; j < nseg * 8; j++) {
        seg_rows[base + j] = 0;       // safe dummy index
        seg_norms[base + j] = 0.0f;   // zero weight -> contributes nothing
    }
}

// Dense matmul fin(N x K) @ W(K x 32) -> xw(N x 32); fused BN+ReLU on input.
// Epilogue also initializes the aggregation buffer: agg[n] = dinv^2*xw[n] + bias
// (the self-loop + bias term), so the gather only needs atomics for edges.
template <int K, bool BN>
__global__ __launch_bounds__(TB) void matmul_kernel(
    const float* __restrict__ fin, const float* __restrict__ W,
    const float* __restrict__ g, const float* __restrict__ be,
    const float* __restrict__ dinv, const float* __restrict__ bias,
    float* __restrict__ xw, float* __restrict__ agg_init, int n_nodes) {
    __shared__ float Ws[K * 32];
    __shared__ float gs[32];
    __shared__ float bs[32];
    __shared__ float bbias[32];
    int tid = threadIdx.x;
    for (int i = tid; i < K * 32; i += TB) Ws[i] = W[i];
    if (tid < 32) {
        bbias[tid] = bias[tid];
        if (BN) {
            gs[tid] = g[tid] * (1.0f / sqrtf(1.0f + 1e-5f));
            bs[tid] = be[tid];
        }
    }
    __syncthreads();
    int n = blockIdx.x * TB + tid;
    if (n >= n_nodes) return;
    float vals[K];
    const float* fp = fin + (size_t)n * K;
    if (K % 4 == 0) {
#pragma unroll
        for (int k = 0; k < K / 4; k++) {
            float4 v = ((const float4*)fp)[k];
            vals[k * 4 + 0] = v.x;
            vals[k * 4 + 1] = v.y;
            vals[k * 4 + 2] = v.z;
            vals[k * 4 + 3] = v.w;
        }
    } else {
#pragma unroll
        for (int k = 0; k < K; k++) vals[k] = fp[k];
    }
    if (BN) {
#pragma unroll
        for (int k = 0; k < K; k++) vals[k] = fmaxf(fmaf(vals[k], gs[k], bs[k]), 0.0f);
    }
    float acc[32];
#pragma unroll
    for (int j = 0; j < 32; j++) acc[j] = 0.0f;
#pragma unroll
    for (int k = 0; k < K; k++) {
        float v = vals[k];
#pragma unroll
        for (int j = 0; j < 32; j++) acc[j] = fmaf(v, Ws[k * 32 + j], acc[j]);
    }
    float4* op = (float4*)(xw + (size_t)n * 32);
#pragma unroll
    for (int j = 0; j < 8; j++)
        op[j] = make_float4(acc[j * 4], acc[j * 4 + 1], acc[j * 4 + 2], acc[j * 4 + 3]);
    float di = dinv[n];
    float dd = di * di;
    float4* ip = (float4*)(agg_init + (size_t)n * 32);
#pragma unroll
    for (int j = 0; j < 8; j++)
        ip[j] = make_float4(fmaf(dd, acc[j * 4 + 0], bbias[j * 4 + 0]),
                            fmaf(dd, acc[j * 4 + 1], bbias[j * 4 + 1]),
                            fmaf(dd, acc[j * 4 + 2], bbias[j * 4 + 2]),
                            fmaf(dd, acc[j * 4 + 3], bbias[j * 4 + 3]));
}

__device__ __forceinline__ float4 f4_fma(float w, float4 v, float4 a) {
    return make_float4(fmaf(w, v.x, a.x), fmaf(w, v.y, a.y),
                       fmaf(w, v.z, a.z), fmaf(w, v.w, a.w));
}

// Segment-parallel gather: one octet (8 lanes) per 8-edge segment.
// Straight-line: 2 aligned vector loads (seg addr independent of any load),
// 8 independent float4 gathers, 8 FMAs, 4 atomics. No loop-carried deps.
__global__ __launch_bounds__(TB) void gather_seg_kernel(
    const int* __restrict__ desc, const int* __restrict__ seg_rows,
    const float* __restrict__ seg_norms, const float4* __restrict__ xw4,
    const int* __restrict__ seg_total, float* __restrict__ agg) {
    int t = blockIdx.x * TB + threadIdx.x;
    int s = t >> 3, f = t & 7;
    if (s >= seg_total[0]) return;
    const int4* rp = (const int4*)(seg_rows + (size_t)s * 8);
    int4 ra = rp[0], rb = rp[1];
    const float4* wp = (const float4*)(seg_norms + (size_t)s * 8);
    float4 wa = wp[0], wb = wp[1];
    float4 v0 = xw4[(size_t)ra.x * 8 + f];
    float4 v1 = xw4[(size_t)ra.y * 8 + f];
    float4 v2 = xw4[(size_t)ra.z * 8 + f];
    float4 v3 = xw4[(size_t)ra.w * 8 + f];
    float4 v4 = xw4[(size_t)rb.x * 8 + f];
    float4 v5 = xw4[(size_t)rb.y * 8 + f];
    float4 v6 = xw4[(size_t)rb.z * 8 + f];
    float4 v7 = xw4[(size_t)rb.w * 8 + f];
    float4 acc = make_float4(0.f, 0.f, 0.f, 0.f);
    acc = f4_fma(wa.x, v0, acc);
    acc = f4_fma(wa.y, v1, acc);
    acc = f4_fma(wa.z, v2, acc);
    acc = f4_fma(wa.w, v3, acc);
    acc = f4_fma(wb.x, v4, acc);
    acc = f4_fma(wb.y, v5, acc);
    acc = f4_fma(wb.z, v6, acc);
    acc = f4_fma(wb.w, v7, acc);
    int n = desc[s];
    float* ap = agg + (size_t)n * 32 + f * 4;
    atomic_add_f32(ap + 0, acc.x);
    atomic_add_f32(ap + 1, acc.y);
    atomic_add_f32(ap + 2, acc.z);
    atomic_add_f32(ap + 3, acc.w);
}

// Graph pooling: read final embeddings, atomically accumulate per-graph sums/counts
__global__ __launch_bounds__(TB) void pool_kernel(
    const float* __restrict__ agg, const int* __restrict__ batch,
    float* __restrict__ sums, float* __restrict__ cnt, int n_nodes) {
    int idx = blockIdx.x * TB + threadIdx.x;
    if (idx >= n_nodes * 8) return;
    int n = idx >> 3, f = idx & 7;
    float4 v = ((const float4*)agg)[(size_t)n * 8 + f];
    int bg = batch[n];
    float* sp = sums + (size_t)bg * 32 + f * 4;
    atomic_add_f32(sp + 0, v.x);
    atomic_add_f32(sp + 1, v.y);
    atomic_add_f32(sp + 2, v.z);
    atomic_add_f32(sp + 3, v.w);
    if (f == 0) atomic_add_f32(&cnt[bg], 1.0f);
}

// pred[g] = sigmoid(dot(sums[g]/max(cnt,1), Wout) + bout)
__global__ __launch_bounds__(TB) void pred_kernel(
    const float* __restrict__ sums, const float* __restrict__ cnt,
    const float* __restrict__ Wout, const float* __restrict__ bout,
    float* __restrict__ out) {
    int g = blockIdx.x * TB + threadIdx.x;
    if (g >= 256) return;
    float c = fmaxf(cnt[g], 1.0f);
    float acc = 0.0f;
#pragma unroll
    for (int j = 0; j < 32; j++) acc += sums[g * 32 + j] * Wout[j];
    float z = acc / c + bout[0];
    out[g] = 1.0f / (1.0f + expf(-z));
}

extern "C" void kernel_launch(void* const* d_in, const int* in_sizes, int n_in,
                              void* d_out, int out_size, void* d_ws, size_t ws_size,
                              hipStream_t stream) {
    const float* x = (const float*)d_in[0];           // (N, 6)
    const int* edge_index = (const int*)d_in[1];      // (2, E)
    const float* pos = (const float*)d_in[2];         // (N, 6)
    const int* batch = (const int*)d_in[3];           // (N,)
    const float* s1 = (const float*)d_in[4];
    const float* s2 = (const float*)d_in[5];
    const float* W1 = (const float*)d_in[6];
    const float* b1 = (const float*)d_in[7];
    const float* W2 = (const float*)d_in[8];
    const float* b2 = (const float*)d_in[9];
    const float* W3 = (const float*)d_in[10];
    const float* b3 = (const float*)d_in[11];
    const float* W4 = (const float*)d_in[12];
    const float* b4 = (const float*)d_in[13];
    const float* g1 = (const float*)d_in[14];
    const float* be1 = (const float*)d_in[15];
    const float* g2 = (const float*)d_in[16];
    const float* be2 = (const float*)d_in[17];
    const float* g3 = (const float*)d_in[18];
    const float* be3 = (const float*)d_in[19];
    const float* Wout = (const float*)d_in[20];
    const float* bout = (const float*)d_in[21];

    const size_t E = (size_t)in_sizes[1] / 2;
    const size_t N = (size_t)in_sizes[3];
    const size_t S_MAX = E / 8 + N;  // upper bound on segment count

    const int* row = edge_index;
    const int* col = edge_index + E;

    auto align256 = [](size_t v) { return (v + 255) & ~(size_t)255; };
    char* w = (char*)d_ws;
    int* seg_rows = (int*)w;    w += align256(S_MAX * 8 * 4);
    float* seg_norms = (float*)w; w += align256(S_MAX * 8 * 4);
    int* desc = (int*)w;        w += align256(S_MAX * 4);
    int* segbase = (int*)w;     w += align256((N + 1) * 4);
    float* bufA = (float*)w;    w += align256(N * 32 * 4);  // xw; also aliases ew
    float* bufB = (float*)w;    w += align256(N * 32 * 4);  // agg (odd layers)
    float* bufC = (float*)w;    w += align256(N * 32 * 4);  // agg (even layers)
    float* dinv = (float*)w;    w += align256(N * 4);       // deg then dinv in place
    int* hist = (int*)w;        w += align256(N * 4);
    int* ptr = (int*)w;         w += align256((N + 1) * 4);
    int* cursor = (int*)w;      w += align256(N * 4);
    float* sums = (float*)w;    w += align256(256 * 32 * 4);
    float* cnt = (float*)w;     w += align256(256 * 4);
    float* ew = bufA;  // dead after fill_kernel; bufA first written by matmul1

    float* out_emb = (float*)d_out;
    float* out_pred = (float*)d_out + N * 32;

    const int gN = (int)((N + TB - 1) / TB);
    const int gE = (int)((E + TB - 1) / TB);
    const int gN8 = (int)((N * 8 + TB - 1) / TB);
    const int gS8 = (int)((S_MAX * 8 + TB - 1) / TB);
    const int* seg_total = segbase + N;

    zero_kernel<<<gN, TB, 0, stream>>>(dinv, hist, sums, cnt, (int)N);
    edge_weight_kernel<<<gE, TB, 0, stream>>>(row, col, (const float2*)pos, s1, s2,
                                              ew, dinv, hist, (int)E);
    dinv_kernel<<<gN, TB, 0, stream>>>(dinv, (int)N);
    scan_kernel<<<1, SCAN_T, 0, stream>>>(hist, ptr, cursor, segbase, (int)N);
    fill_kernel<<<gE, TB, 0, stream>>>(row, col, ew, dinv, cursor, ptr, segbase,
                                       seg_rows, seg_norms, (int)E);
    segfill_kernel<<<gN, TB, 0, stream>>>(ptr, segbase, desc, seg_rows, seg_norms, (int)N);

    // Layer 1: x (N,6) @ W1 -> bufA(xw), init bufB; gather edges into bufB
    matmul_kernel<6, false><<<gN, TB, 0, stream>>>(x, W1, nullptr, nullptr, dinv, b1,
                                                   bufA, bufB, (int)N);
    gather_seg_kernel<<<gS8, TB, 0, stream>>>(desc, seg_rows, seg_norms,
                                              (const float4*)bufA, seg_total, bufB);
    // Layer 2: relu(bn1(bufB)) @ W2 -> bufA, init bufC; gather -> bufC
    matmul_kernel<32, true><<<gN, TB, 0, stream>>>(bufB, W2, g1, be1, dinv, b2,
                                                   bufA, bufC, (int)N);
    gather_seg_kernel<<<gS8, TB, 0, stream>>>(desc, seg_rows, seg_norms,
                                              (const float4*)bufA, seg_total, bufC);
    // Layer 3: bufC -> bufA, init bufB; gather -> bufB
    matmul_kernel<32, true><<<gN, TB, 0, stream>>>(bufC, W3, g2, be2, dinv, b3,
                                                   bufA, bufB, (int)N);
    gather_seg_kernel<<<gS8, TB, 0, stream>>>(desc, seg_rows, seg_norms,
                                              (const float4*)bufA, seg_total, bufB);
    // Layer 4: bufB -> bufA, init out_emb; gather -> out_emb
    matmul_kernel<32, true><<<gN, TB, 0, stream>>>(bufB, W4, g3, be3, dinv, b4,
                                                   bufA, out_emb, (int)N);
    gather_seg_kernel<<<gS8, TB, 0, stream>>>(desc, seg_rows, seg_norms,
                                              (const float4*)bufA, seg_total, out_emb);

    pool_kernel<<<gN8, TB, 0, stream>>>(out_emb, batch, sums, cnt, (int)N);
    pred_kernel<<<1, TB, 0, stream>>>(sums, cnt, Wout, bout, out_pred);
}